// Round 4
// baseline (1592.654 us; speedup 1.0000x reference)
//
#include <hip/hip_runtime.h>
#include <hip/hip_bf16.h>
#include <math.h>

// ---------------- problem constants ----------------
#define DIMK 1024
#define HD   128
#define AHR  6208      // 4*1536 + 64 rows of "all_hiddens" per batch
#define LME  256       // LMEM_LEN
#define NB   8         // batch
#define LMROWS 2048    // NB*LME
#define KROWS  8192    // NB*DIMK  (softmax-k stat rows)
#define NBC  2         // batches per precompute chunk

typedef __attribute__((ext_vector_type(8))) short s16x8;
typedef __attribute__((ext_vector_type(4))) float f32x4;
typedef __attribute__((ext_vector_type(4))) unsigned short u16x4;

__device__ __forceinline__ float bf2f(unsigned short u){
  union { unsigned int i; float f; } c; c.i = ((unsigned int)u) << 16; return c.f;
}
__device__ __forceinline__ unsigned short f2bf(float f){
  union { float f; unsigned int i; } c; c.f = f;
  unsigned int r = c.i + 0x7fffu + ((c.i >> 16) & 1u);
  return (unsigned short)(r >> 16);
}

// ---------------- workspace layout (bytes), peak ~113.4 MB ----------------
// persistent
#define OFF_BTQKV  0ull            // bf16 [3072][1024]
#define OFF_BTWOUT 6291456ull      // bf16 [1024][1024]
#define OFF_BTX    8388608ull      // bf16 [3072][1024]
#define OFF_BTH    14680064ull     // bf16 [2048][1024]
#define OFF_MAXAH  18874368ull     // f32 [8192]
#define OFF_SUMAH  18907136ull     // f32 [8192]
#define OFF_SCB    18939904ull     // f32 [8192]
#define OFF_STB    18972672ull     // f32 [8192]
#define OFF_CTXAHT 19005440ull     // f32 [64][128e][128d]
#define OFF_NL     23199744ull     // f32 [2048][1024]
#define OFF_SCR    31588352ull     // scratch base (aliased regions below)
// phase-1 scratch (per 2-batch chunk)
#define OFF_AHC    (OFF_SCR + 0ull)          // bf16 [2][6208][1024]
#define OFF_AHKC   (OFF_SCR + 25427968ull)   // bf16 [2][1024][6208]
#define OFF_AHVC   (OFF_SCR + 50855936ull)   // bf16 [2][1024][6208]
// phase-2 scratch (aliases phase-1)
#define OFF_NX     (OFF_SCR + 0ull)          // bf16 [2048][1024]
#define OFF_HBF    (OFF_SCR + 4194304ull)    // bf16 [2048][1024]
#define OFF_Q      (OFF_SCR + 8388608ull)    // f32  [2048][1024]
#define OFF_QSM    (OFF_SCR + 16777216ull)   // bf16 [2048][1024]
#define OFF_NXK    (OFF_SCR + 20971520ull)   // bf16 [8][1024][256]
#define OFF_NXV    (OFF_SCR + 25165824ull)   // bf16 [8][1024][256]
#define OFF_CTXT   (OFF_SCR + 29360128ull)   // bf16 [64][128e][128d]
#define OFF_OUTB   (OFF_SCR + 31457280ull)   // bf16 [2048][1024]
#define OFF_XB     (OFF_SCR + 35651584ull)   // bf16 [2048][1024]
#define OFF_GX     (OFF_SCR + 39845888ull)   // f32  [2048][3072]
#define OFF_GH     (OFF_SCR + 65011712ull)   // f32  [2048][2048]  (ends at 81,788,928)
#define OUT_LMEM_OFF 33554432ull   // float elements

// ---------------- async global->LDS ----------------
#define AS1 __attribute__((address_space(1)))
#define AS3 __attribute__((address_space(3)))
__device__ __forceinline__ void gl16(const unsigned short* g, unsigned short* l){
  __builtin_amdgcn_global_load_lds((const AS1 unsigned int*)(g), (AS3 unsigned int*)(l), 16, 0, 0);
}

// =====================================================================
// Generic bf16 BT-GEMM: C[m,n] = sum_k A[m,k]*Bt[n,k]  (128x128 tile, BK=32)
// 256 threads = 4 waves, each wave a 64x64 quadrant via 4x4 16x16x32 MFMAs.
// =====================================================================
template<int EPI>
__global__ __launch_bounds__(256, 2)
void gemm_bt(const unsigned short* __restrict__ A, long long astr,
             const unsigned short* __restrict__ Bt, long long bstr,
             int M, int N, int K, int lda, int ldb, int ldc, int zoff,
             void* p0, void* p1, void* p2, void* p3)
{
  __shared__ unsigned short As[128*32];
  __shared__ unsigned short Bs[128*32];
  const int tid  = threadIdx.x;
  const int lane = tid & 63;
  const int wv   = tid >> 6;
  const int z    = blockIdx.z;
  const int m0 = blockIdx.x * 128, n0 = blockIdx.y * 128;

  const unsigned short* Ab = A + (size_t)z * astr;
  if constexpr (EPI == 4) Ab = A + (size_t)(z >> 3) * LME * DIMK + (size_t)(z & 7) * HD;
  const unsigned short* Bb = Bt + (size_t)z * bstr;

  const int i0 = tid, i1 = tid + 256;
  int ar0 = m0 + (i0 >> 2); if (ar0 > M - 1) ar0 = M - 1;
  int ar1 = m0 + (i1 >> 2); if (ar1 > M - 1) ar1 = M - 1;
  const unsigned short* ag0 = Ab + (size_t)ar0 * lda + (i0 & 3) * 8;
  const unsigned short* ag1 = Ab + (size_t)ar1 * lda + (i1 & 3) * 8;
  const unsigned short* bg0 = Bb + (size_t)(n0 + (i0 >> 2)) * ldb + (i0 & 3) * 8;
  const unsigned short* bg1 = Bb + (size_t)(n0 + (i1 >> 2)) * ldb + (i1 & 3) * 8;
  unsigned short* al0 = As + i0 * 8;  unsigned short* al1 = As + i1 * 8;
  unsigned short* bl0 = Bs + i0 * 8;  unsigned short* bl1 = Bs + i1 * 8;

  const int wr = (wv >> 1) * 64, wc = (wv & 1) * 64;
  const int fr = lane & 15, kg = lane >> 4;

  f32x4 acc[4][4];
  #pragma unroll
  for (int i = 0; i < 4; i++)
    #pragma unroll
    for (int j = 0; j < 4; j++) acc[i][j] = (f32x4){0.f, 0.f, 0.f, 0.f};

  for (int k0 = 0; k0 < K; k0 += 32) {
    gl16(ag0 + k0, al0);
    gl16(ag1 + k0, al1);
    gl16(bg0 + k0, bl0);
    gl16(bg1 + k0, bl1);
    __syncthreads();
    s16x8 af[4], bf[4];
    #pragma unroll
    for (int i = 0; i < 4; i++) {
      af[i] = *(const s16x8*)&As[(wr + i * 16 + fr) * 32 + kg * 8];
      bf[i] = *(const s16x8*)&Bs[(wc + i * 16 + fr) * 32 + kg * 8];
    }
    #pragma unroll
    for (int i = 0; i < 4; i++)
      #pragma unroll
      for (int j = 0; j < 4; j++)
        acc[i][j] = __builtin_amdgcn_mfma_f32_16x16x32_bf16(af[i], bf[j], acc[i][j], 0, 0, 0);
    __syncthreads();
  }

  // epilogue: lane owns col, rows row..row+3 (verified C/D layout)
  #pragma unroll
  for (int i = 0; i < 4; i++) {
    const int row = m0 + wr + i * 16 + kg * 4;
    #pragma unroll
    for (int j = 0; j < 4; j++) {
      const int col = n0 + wc + j * 16 + fr;
      f32x4 v = acc[i][j];
      if constexpr (EPI == 0) {          // f32 normal
        float* out = (float*)p0;
        #pragma unroll
        for (int r = 0; r < 4; r++) if (row + r < M) out[(size_t)(row + r) * ldc + col] = v[r];
      } else if constexpr (EPI == 1) {   // bf16 normal
        unsigned short* out = (unsigned short*)p0;
        #pragma unroll
        for (int r = 0; r < 4; r++) if (row + r < M) out[(size_t)(row + r) * ldc + col] = f2bf(v[r]);
      } else if constexpr (EPI == 2) {   // ah KV: transposed bf16 dual (K cols<1024, V rest)
        if (row < M) {
          unsigned short* out = (col < DIMK)
            ? ((unsigned short*)p0 + ((size_t)z * DIMK + col) * AHR)
            : ((unsigned short*)p1 + ((size_t)z * DIMK + (col - DIMK)) * AHR);
          u16x4 o;
          #pragma unroll
          for (int r = 0; r < 4; r++) o[r] = f2bf(v[r]);
          *(u16x4*)&out[row] = o;
        }
      } else if constexpr (EPI == 3) {   // nx qkv: q f32 normal; k,v transposed bf16
        if (col < DIMK) {
          float* q = (float*)p0;
          #pragma unroll
          for (int r = 0; r < 4; r++) q[(size_t)(row + r) * DIMK + col] = v[r];
        } else {
          const int b = row >> 8, n = row & 255;
          unsigned short* out = (col < 2 * DIMK)
            ? ((unsigned short*)p1 + ((size_t)b * DIMK + (col - DIMK)) * LME)
            : ((unsigned short*)p2 + ((size_t)b * DIMK + (col - 2 * DIMK)) * LME);
          u16x4 o;
          #pragma unroll
          for (int r = 0; r < 4; r++) o[r] = f2bf(v[r]);
          *(u16x4*)&out[n] = o;
        }
      } else if constexpr (EPI == 4) {   // qsm@ctx -> outb bf16 at head offset
        unsigned short* out = (unsigned short*)p0 + (size_t)(z >> 3) * LME * DIMK + (size_t)(z & 7) * HD;
        #pragma unroll
        for (int r = 0; r < 4; r++) out[(size_t)(row + r) * DIMK + col] = f2bf(v[r]);
      } else if constexpr (EPI == 5) {   // ctx_nx + online-softmax combine -> ctxT bf16
        const int sb = (z >> 3) * DIMK + (z & 7) * HD;
        const float* scb = (const float*)p1;
        const float* stb = (const float*)p2;
        f32x4 cah = *(const f32x4*)((const float*)p3 + (size_t)z * 16384 + (size_t)col * HD + row);
        u16x4 o;
        #pragma unroll
        for (int r = 0; r < 4; r++) {
          float sc = scb[sb + row + r], st = stb[sb + row + r];
          o[r] = f2bf((sc * cah[r] + v[r]) / st);
        }
        *(u16x4*)((unsigned short*)p0 + (size_t)z * 16384 + (size_t)col * HD + row) = o;
      } else if constexpr (EPI == 6) {   // ctx_ah transposed f32 (zoff = chunk*16)
        float* out = (float*)p0 + (size_t)(z + zoff) * 16384 + (size_t)col * HD + row;
        *(f32x4*)out = v;
      }
    }
  }
}

// =====================================================================
// weight prep: transpose f32 (RxC) -> bf16 (CxR); 3 matrices routed by block
// =====================================================================
__global__ void k_transpose(const float* __restrict__ wq, const float* __restrict__ wkv,
                            const float* __restrict__ wout,
                            unsigned short* __restrict__ btqkv, unsigned short* __restrict__ btwout)
{
  const int bid = blockIdx.x;
  const float* src; unsigned short* dst; int R, C, bx, by;
  if (bid < 256)      { src = wq;   dst = btqkv;               R = 1024; C = 1024; bx = bid & 15;        by = bid >> 4; }
  else if (bid < 768) { src = wkv;  dst = btqkv + 1024 * 1024; R = 1024; C = 2048; bx = (bid-256) & 31;  by = (bid-256) >> 5; }
  else                { src = wout; dst = btwout;              R = 1024; C = 1024; bx = (bid-768) & 15;  by = (bid-768) >> 4; }
  __shared__ float tile[64][65];
  const int r0 = by * 64, c0 = bx * 64;
  const int tid = threadIdx.x;
  const int tr = tid >> 4, tc = (tid & 15) * 4;
  #pragma unroll
  for (int p = 0; p < 4; p++) {
    int r = p * 16 + tr;
    f32x4 v = *(const f32x4*)&src[(size_t)(r0 + r) * C + c0 + tc];
    tile[r][tc] = v.x; tile[r][tc+1] = v.y; tile[r][tc+2] = v.z; tile[r][tc+3] = v.w;
  }
  __syncthreads();
  #pragma unroll
  for (int p = 0; p < 4; p++) {
    int cc = p * 16 + tr;
    int rr = tc;
    u16x4 o;
    #pragma unroll
    for (int j = 0; j < 4; j++) o[j] = f2bf(tile[rr + j][cc]);
    *(u16x4*)&dst[(size_t)(c0 + cc) * R + r0 + rr] = o;
  }
}

// gate weights: straight f32->bf16 copies into concatenated BT buffers
__global__ void k_copy(const float* __restrict__ ua, const float* __restrict__ uc,
                       const float* __restrict__ uw, const float* __restrict__ wa,
                       const float* __restrict__ wc,
                       unsigned short* __restrict__ btx, unsigned short* __restrict__ bth)
{
  size_t i = ((size_t)blockIdx.x * 256 + threadIdx.x) * 4;
  const float* src; unsigned short* dst; size_t off;
  if (i < 1048576)      { src = ua; dst = btx;            off = i; }
  else if (i < 2097152) { src = uc; dst = btx + 1048576;  off = i - 1048576; }
  else if (i < 3145728) { src = uw; dst = btx + 2097152;  off = i - 2097152; }
  else if (i < 4194304) { src = wa; dst = bth;            off = i - 3145728; }
  else                  { src = wc; dst = bth + 1048576;  off = i - 4194304; }
  f32x4 v = *(const f32x4*)&src[off];
  u16x4 o; o.x = f2bf(v.x); o.y = f2bf(v.y); o.z = f2bf(v.z); o.w = f2bf(v.w);
  *(u16x4*)&dst[off] = o;
}

// build ah bf16 for one 2-batch chunk: (smem,hiddens)+depth_emb, then mem_kv rows
__global__ void k_build_ah(const float* __restrict__ smem, const float* __restrict__ hid,
                           const float* __restrict__ memkv, const float* __restrict__ demb,
                           int b0, unsigned short* __restrict__ ah)
{
  size_t i = ((size_t)blockIdx.x * 256 + threadIdx.x) * 4;
  if (i >= (size_t)NBC * AHR * DIMK) return;
  const int k = (int)(i & 1023);
  const size_t row = i >> 10;
  const int bl = (int)(row / AHR);
  const int j  = (int)(row - (size_t)bl * AHR);
  const int b  = b0 + bl;
  const float* src; float add = 0.f;
  if (j < 6144) {
    int d = j / 1536, p = j - d * 1536;
    add = demb[d];
    if (p < 1024) src = smem + (((size_t)d * NB + b) * 1024 + p) * 1024 + k;
    else          src = hid  + (((size_t)d * NB + b) * 512 + (p - 1024)) * 1024 + k;
  } else {
    src = memkv + (size_t)(j - 6144) * 1024 + k;
  }
  f32x4 v = *(const f32x4*)src;
  u16x4 o; o.x = f2bf(v.x + add); o.y = f2bf(v.y + add); o.z = f2bf(v.z + add); o.w = f2bf(v.w + add);
  *(u16x4*)&ah[i] = o;
}

__global__ void k_init_lmem(const float* __restrict__ lmem, const float* __restrict__ pos,
                            float* __restrict__ nl)
{
  size_t i = ((size_t)blockIdx.x * 256 + threadIdx.x) * 4;
  const int m = (int)(i >> 10), c = (int)(i & 1023);
  f32x4 a = *(const f32x4*)&lmem[i];
  f32x4 p = *(const f32x4*)&pos[(size_t)(m & 255) * 1024 + c];
  a.x += p.x; a.y += p.y; a.z += p.z; a.w += p.w;
  *(f32x4*)&nl[i] = a;
}

// per (b,e) row of ahK chunk: max over 6208, exp in place, sum; store stats
__global__ void k_expmax(unsigned short* __restrict__ ahK, float* __restrict__ maxah,
                         float* __restrict__ sumah)
{
  const int row = blockIdx.x;
  const int tid = threadIdx.x;
  unsigned short* p = ahK + (size_t)row * AHR;
  float mx = -1e30f;
  for (int i = tid; i < AHR; i += 256) mx = fmaxf(mx, bf2f(p[i]));
  #pragma unroll
  for (int off = 32; off; off >>= 1) mx = fmaxf(mx, __shfl_xor(mx, off));
  __shared__ float red[8];
  if ((tid & 63) == 0) red[tid >> 6] = mx;
  __syncthreads();
  mx = fmaxf(fmaxf(red[0], red[1]), fmaxf(red[2], red[3]));
  float s = 0.f;
  for (int i = tid; i < AHR; i += 256) {
    float e = expf(bf2f(p[i]) - mx);
    p[i] = f2bf(e);
    s += e;
  }
  #pragma unroll
  for (int off = 32; off; off >>= 1) s += __shfl_xor(s, off);
  __shared__ float red2[8];
  if ((tid & 63) == 0) red2[tid >> 6] = s;
  __syncthreads();
  if (tid == 0) { maxah[row] = mx; sumah[row] = red2[0] + red2[1] + red2[2] + red2[3]; }
}

// per (b,e) row of nxK (256 wide): combined max with max_ah, exp in place, totals
__global__ void k_kmax(unsigned short* __restrict__ nxK, const float* __restrict__ maxah,
                       const float* __restrict__ sumah, float* __restrict__ scb,
                       float* __restrict__ stb)
{
  const int row = blockIdx.x;
  const int t = threadIdx.x;
  unsigned short* p = nxK + (size_t)row * LME + t * 4;
  u16x4 v = *(u16x4*)p;
  float f0 = bf2f(v.x), f1 = bf2f(v.y), f2 = bf2f(v.z), f3 = bf2f(v.w);
  float mx = fmaxf(fmaxf(f0, f1), fmaxf(f2, f3));
  #pragma unroll
  for (int off = 32; off; off >>= 1) mx = fmaxf(mx, __shfl_xor(mx, off));
  const float mah = maxah[row];
  const float m = fmaxf(mx, mah);
  float e0 = expf(f0 - m), e1 = expf(f1 - m), e2 = expf(f2 - m), e3 = expf(f3 - m);
  float s = e0 + e1 + e2 + e3;
  #pragma unroll
  for (int off = 32; off; off >>= 1) s += __shfl_xor(s, off);
  u16x4 o; o.x = f2bf(e0); o.y = f2bf(e1); o.z = f2bf(e2); o.w = f2bf(e3);
  *(u16x4*)p = o;
  if (t == 0) { float sc = expf(mah - m); scb[row] = sc; stb[row] = sc * sumah[row] + s; }
}

// LN of next_lmem rows -> nx bf16 + h bf16 copy
__global__ void k_ln_nx(const float* __restrict__ nl, unsigned short* __restrict__ nx,
                        unsigned short* __restrict__ hb)
{
  const int m = blockIdx.x, tid = threadIdx.x;
  f32x4 v = *(const f32x4*)&nl[(size_t)m * DIMK + tid * 4];
  float s = v.x + v.y + v.z + v.w;
  float q = v.x*v.x + v.y*v.y + v.z*v.z + v.w*v.w;
  __shared__ float red[16];
  #pragma unroll
  for (int off = 32; off; off >>= 1) { s += __shfl_down(s, off); q += __shfl_down(q, off); }
  if ((tid & 63) == 0) { red[tid >> 6] = s; red[8 + (tid >> 6)] = q; }
  __syncthreads();
  s = red[0] + red[1] + red[2] + red[3];
  q = red[8] + red[9] + red[10] + red[11];
  const float mean = s * (1.f / 1024.f);
  const float rstd = rsqrtf(q * (1.f / 1024.f) - mean * mean + 1e-5f);
  u16x4 a, b;
  a.x = f2bf((v.x - mean) * rstd); a.y = f2bf((v.y - mean) * rstd);
  a.z = f2bf((v.z - mean) * rstd); a.w = f2bf((v.w - mean) * rstd);
  b.x = f2bf(v.x); b.y = f2bf(v.y); b.z = f2bf(v.z); b.w = f2bf(v.w);
  *(u16x4*)&nx[(size_t)m * DIMK + tid * 4] = a;
  *(u16x4*)&hb[(size_t)m * DIMK + tid * 4] = b;
}

// final out_lmem: LN(next_lmem)*g+b -> f32 out
__global__ void k_ln_out(const float* __restrict__ nl, const float* __restrict__ g,
                         const float* __restrict__ bt, float* __restrict__ out)
{
  const int m = blockIdx.x, tid = threadIdx.x;
  f32x4 v = *(const f32x4*)&nl[(size_t)m * DIMK + tid * 4];
  float s = v.x + v.y + v.z + v.w;
  float q = v.x*v.x + v.y*v.y + v.z*v.z + v.w*v.w;
  __shared__ float red[16];
  #pragma unroll
  for (int off = 32; off; off >>= 1) { s += __shfl_down(s, off); q += __shfl_down(q, off); }
  if ((tid & 63) == 0) { red[tid >> 6] = s; red[8 + (tid >> 6)] = q; }
  __syncthreads();
  s = red[0] + red[1] + red[2] + red[3];
  q = red[8] + red[9] + red[10] + red[11];
  const float mean = s * (1.f / 1024.f);
  const float rstd = rsqrtf(q * (1.f / 1024.f) - mean * mean + 1e-5f);
  f32x4 gg = *(const f32x4*)&g[tid * 4];
  f32x4 bb = *(const f32x4*)&bt[tid * 4];
  f32x4 o;
  o.x = (v.x - mean) * rstd * gg.x + bb.x;
  o.y = (v.y - mean) * rstd * gg.y + bb.y;
  o.z = (v.z - mean) * rstd * gg.z + bb.z;
  o.w = (v.w - mean) * rstd * gg.w + bb.w;
  *(f32x4*)&out[(size_t)m * DIMK + tid * 4] = o;
}

// out_mem: LN of queue[:, :, -1024:, :] rows straight from smem/hiddens -> f32 out
__global__ void k_ln_mem(const float* __restrict__ smem, const float* __restrict__ hid,
                         const float* __restrict__ g, const float* __restrict__ bt,
                         float* __restrict__ out)
{
  const int mrow = blockIdx.x;           // 0..32767  = ((d*8+b)*1024 + r)
  const int tid = threadIdx.x;
  const int d = mrow >> 13, b = (mrow >> 10) & 7, r = mrow & 1023;
  const float* src = (r < 512)
    ? smem + (((size_t)d * NB + b) * 1024 + 512 + r) * 1024
    : hid  + (((size_t)d * NB + b) * 512 + (r - 512)) * 1024;
  f32x4 v = *(const f32x4*)&src[tid * 4];
  float s = v.x + v.y + v.z + v.w;
  float q = v.x*v.x + v.y*v.y + v.z*v.z + v.w*v.w;
  __shared__ float red[16];
  #pragma unroll
  for (int off = 32; off; off >>= 1) { s += __shfl_down(s, off); q += __shfl_down(q, off); }
  if ((tid & 63) == 0) { red[tid >> 6] = s; red[8 + (tid >> 6)] = q; }
  __syncthreads();
  s = red[0] + red[1] + red[2] + red[3];
  q = red[8] + red[9] + red[10] + red[11];
  const float mean = s * (1.f / 1024.f);
  const float rstd = rsqrtf(q * (1.f / 1024.f) - mean * mean + 1e-5f);
  f32x4 gg = *(const f32x4*)&g[tid * 4];
  f32x4 bb = *(const f32x4*)&bt[tid * 4];
  f32x4 o;
  o.x = (v.x - mean) * rstd * gg.x + bb.x;
  o.y = (v.y - mean) * rstd * gg.y + bb.y;
  o.z = (v.z - mean) * rstd * gg.z + bb.z;
  o.w = (v.w - mean) * rstd * gg.w + bb.w;
  *(f32x4*)&out[(size_t)mrow * DIMK + tid * 4] = o;
}

// q softmax over head dim (128) -> bf16
__global__ void k_qsm(const float* __restrict__ q, unsigned short* __restrict__ qs)
{
  const int m = blockIdx.x, tid = threadIdx.x;
  const int h = tid >> 5, i4 = (tid & 31) * 4;
  f32x4 v = *(const f32x4*)&q[(size_t)m * DIMK + h * HD + i4];
  float mx = fmaxf(fmaxf(v.x, v.y), fmaxf(v.z, v.w));
  #pragma unroll
  for (int off = 16; off; off >>= 1) mx = fmaxf(mx, __shfl_xor(mx, off, 32));
  float e0 = expf(v.x - mx), e1 = expf(v.y - mx), e2 = expf(v.z - mx), e3 = expf(v.w - mx);
  float s = e0 + e1 + e2 + e3;
  #pragma unroll
  for (int off = 16; off; off >>= 1) s += __shfl_xor(s, off, 32);
  const float inv = 1.f / s;
  u16x4 o; o.x = f2bf(e0 * inv); o.y = f2bf(e1 * inv); o.z = f2bf(e2 * inv); o.w = f2bf(e3 * inv);
  *(u16x4*)&qs[(size_t)m * DIMK + h * HD + i4] = o;
}

// gate elementwise: next_lmem = c*h + (1-c)*tanh(Ux + U_b + a*h)
__global__ void k_gate(const float* __restrict__ Gx, const float* __restrict__ Gh,
                       float* __restrict__ nl,
                       const float* __restrict__ uab, const float* __restrict__ wab,
                       const float* __restrict__ ucb, const float* __restrict__ wcb,
                       const float* __restrict__ ub)
{
  const int m = blockIdx.x, c = threadIdx.x * 4;
  f32x4 xa = *(const f32x4*)&Gx[(size_t)m * 3072 + c];
  f32x4 xc = *(const f32x4*)&Gx[(size_t)m * 3072 + 1024 + c];
  f32x4 xu = *(const f32x4*)&Gx[(size_t)m * 3072 + 2048 + c];
  f32x4 ha = *(const f32x4*)&Gh[(size_t)m * 2048 + c];
  f32x4 hc = *(const f32x4*)&Gh[(size_t)m * 2048 + 1024 + c];
  f32x4 hv = *(const f32x4*)&nl[(size_t)m * 1024 + c];
  f32x4 b1 = *(const f32x4*)&uab[c];
  f32x4 b2 = *(const f32x4*)&wab[c];
  f32x4 b3 = *(const f32x4*)&ucb[c];
  f32x4 b4 = *(const f32x4*)&wcb[c];
  f32x4 b5 = *(const f32x4*)&ub[c];
  f32x4 o;
  #pragma unroll
  for (int r = 0; r < 4; r++) {
    float a  = 1.f + tanhf(xa[r] + b1[r] + ha[r] + b2[r]);
    float cc = 1.f / (1.f + expf(-(xc[r] + b3[r] + hc[r] + b4[r])));
    float t  = tanhf(xu[r] + b5[r] + a * hv[r]);
    o[r] = cc * hv[r] + (1.f - cc) * t;
  }
  *(f32x4*)&nl[(size_t)m * 1024 + c] = o;
}

// =====================================================================
extern "C" void kernel_launch(void* const* d_in, const int* in_sizes, int n_in,
                              void* d_out, int out_size, void* d_ws, size_t ws_size,
                              hipStream_t stream)
{
  const float* lmem    = (const float*)d_in[0];
  const float* smem    = (const float*)d_in[1];
  const float* hiddens = (const float*)d_in[2];
  const float* w_q     = (const float*)d_in[3];
  const float* w_kv    = (const float*)d_in[4];
  const float* w_out   = (const float*)d_in[5];
  const float* demb    = (const float*)d_in[6];
  const float* lpos    = (const float*)d_in[7];
  const float* memkv   = (const float*)d_in[8];
  const float* Ua_w = (const float*)d_in[9];  const float* Ua_b = (const float*)d_in[10];
  const float* Wa_w = (const float*)d_in[11]; const float* Wa_b = (const float*)d_in[12];
  const float* Uc_w = (const float*)d_in[13]; const float* Uc_b = (const float*)d_in[14];
  const float* Wc_w = (const float*)d_in[15]; const float* Wc_b = (const float*)d_in[16];
  const float* U_w  = (const float*)d_in[17]; const float* U_b  = (const float*)d_in[18];
  const float* n1g = (const float*)d_in[19];  const float* n1b = (const float*)d_in[20];
  const float* n2g = (const float*)d_in[21];  const float* n2b = (const float*)d_in[22];

  char* ws = (char*)d_ws;
  unsigned short* btqkv = (unsigned short*)(ws + OFF_BTQKV);
  unsigned short* btwo  = (unsigned short*)(ws + OFF_BTWOUT);
  unsigned short* btx   = (unsigned short*)(ws + OFF_BTX);
  unsigned short* bth   = (unsigned short*)(ws + OFF_BTH);
  float* maxah  = (float*)(ws + OFF_MAXAH);
  float* sumah  = (float*)(ws + OFF_SUMAH);
  float* scb    = (float*)(ws + OFF_SCB);
  float* stb    = (float*)(ws + OFF_STB);
  float* ctxahT = (float*)(ws + OFF_CTXAHT);
  float* nl     = (float*)(ws + OFF_NL);
  unsigned short* ahc  = (unsigned short*)(ws + OFF_AHC);
  unsigned short* ahKc = (unsigned short*)(ws + OFF_AHKC);
  unsigned short* ahVc = (unsigned short*)(ws + OFF_AHVC);
  unsigned short* nx   = (unsigned short*)(ws + OFF_NX);
  unsigned short* hbf  = (unsigned short*)(ws + OFF_HBF);
  float* qf            = (float*)(ws + OFF_Q);
  unsigned short* qsm  = (unsigned short*)(ws + OFF_QSM);
  unsigned short* nxK  = (unsigned short*)(ws + OFF_NXK);
  unsigned short* nxV  = (unsigned short*)(ws + OFF_NXV);
  unsigned short* ctxT = (unsigned short*)(ws + OFF_CTXT);
  unsigned short* outb = (unsigned short*)(ws + OFF_OUTB);
  unsigned short* xb   = (unsigned short*)(ws + OFF_XB);
  float* Gx            = (float*)(ws + OFF_GX);
  float* Gh            = (float*)(ws + OFF_GH);
  float* out           = (float*)d_out;   // f32 output (reference output dtype)

  // ---- once: weights, initial lmem ----
  k_transpose<<<1024, 256, 0, stream>>>(w_q, w_kv, w_out, btqkv, btwo);
  k_copy<<<5120, 256, 0, stream>>>(Ua_w, Uc_w, U_w, Wa_w, Wc_w, btx, bth);
  k_init_lmem<<<2048, 256, 0, stream>>>(lmem, lpos, nl);

  // ---- ah K/V + softmax-k stats + ctx_ah, chunked by 2 batches (~113 MB peak ws) ----
  for (int c = 0; c < NB / NBC; c++) {
    k_build_ah<<<12416, 256, 0, stream>>>(smem, hiddens, memkv, demb, c * NBC, ahc);
    gemm_bt<2><<<dim3(49, 16, NBC), 256, 0, stream>>>(
        ahc, (long long)AHR * DIMK, btqkv + 1024 * 1024, 0,
        AHR, 2048, 1024, 1024, 1024, 0, 0, ahKc, ahVc, nullptr, nullptr);
    k_expmax<<<NBC * 1024, 256, 0, stream>>>(ahKc, maxah + c * NBC * 1024, sumah + c * NBC * 1024);
    gemm_bt<6><<<dim3(1, 1, NBC * 8), 256, 0, stream>>>(
        ahKc, (long long)128 * AHR, ahVc, (long long)128 * AHR,
        128, 128, AHR, AHR, AHR, 0, c * NBC * 8, ctxahT, nullptr, nullptr, nullptr);
  }

  // ---- MEM_WRITE_ITERS = 2 ----
  for (int it = 0; it < 2; it++) {
    k_ln_nx<<<LMROWS, 256, 0, stream>>>(nl, nx, hbf);
    // [q | k_nx | v_nx] = nx @ Bt_qkv
    gemm_bt<3><<<dim3(16, 24, 1), 256, 0, stream>>>(
        nx, 0, btqkv, 0, LMROWS, 3072, 1024, 1024, 1024, 0, 0, qf, nxK, nxV, nullptr);
    k_kmax<<<KROWS, 64, 0, stream>>>(nxK, maxah, sumah, scb, stb);
    // ctx = (sc*ctx_ah + Kexp_nx^T V_nx)/S  -> ctxT bf16
    gemm_bt<5><<<dim3(1, 1, 64), 256, 0, stream>>>(
        nxK, 32768, nxV, 32768, 128, 128, 256, 256, 256, 0, 0,
        ctxT, scb, stb, ctxahT);
    k_qsm<<<LMROWS, 256, 0, stream>>>(qf, qsm);
    // out = qsm @ ctx   (per (b,h))
    gemm_bt<4><<<dim3(2, 1, 64), 256, 0, stream>>>(
        qsm, 0, ctxT, 16384, 256, 128, 128, 1024, 128, 0, 0,
        outb, nullptr, nullptr, nullptr);
    // attn_out = out @ w_out^T
    gemm_bt<1><<<dim3(16, 8, 1), 256, 0, stream>>>(
        outb, 0, btwo, 0, LMROWS, 1024, 1024, 1024, 1024, 1024, 0,
        xb, nullptr, nullptr, nullptr);
    // gate linears
    gemm_bt<0><<<dim3(16, 24, 1), 256, 0, stream>>>(
        xb, 0, btx, 0, LMROWS, 3072, 1024, 1024, 1024, 3072, 0,
        Gx, nullptr, nullptr, nullptr);
    gemm_bt<0><<<dim3(16, 16, 1), 256, 0, stream>>>(
        hbf, 0, bth, 0, LMROWS, 2048, 1024, 1024, 1024, 2048, 0,
        Gh, nullptr, nullptr, nullptr);
    k_gate<<<LMROWS, 256, 0, stream>>>(Gx, Gh, nl, Ua_b, Wa_b, Uc_b, Wc_b, U_b);
  }

  // ---- outputs (f32) ----
  k_ln_out<<<LMROWS, 256, 0, stream>>>(nl, n2g, n2b, out + OUT_LMEM_OFF);
  k_ln_mem<<<32768, 256, 0, stream>>>(smem, hiddens, n1g, n1b, out);
}